// Round 16
// baseline (64.816 us; speedup 1.0000x reference)
//
#include <hip/hip_runtime.h>
#include <hip/hip_bf16.h>

#define HOP 256
#define NB 16
#define NT 1024
#define MM (NB*NT)                 // 16384
#define LOUT ((NT-1)*HOP + 1024)   // 262912
#define CQ (2.0f/(3.0f*1024.0f))   // (HOP/sum(win^2))/NFFT
#define PACK_BLOCKS 2048           // 16 b x 8 f-tiles x 16 t-tiles

typedef __bf16 bf16x8 __attribute__((ext_vector_type(8)));
typedef float f32x4 __attribute__((ext_vector_type(4)));

__device__ __forceinline__ void gload_lds16(const void* g, void* l) {
  __builtin_amdgcn_global_load_lds(
      (const __attribute__((address_space(1))) void*)g,
      (__attribute__((address_space(3))) void*)l, 16, 0, 0);
}

// Radix-2 frequency split, E/O as separate GEMM panels.
// A2[m][c]: c in [0,257): re f=2c | [257,512): im f=2(c-256) | [512,768): re f=2(c-512)+1
//   | [768,1024): im f=2(c-768)+1.  (im f=0 dropped: zero kernel; re f=512 at c=256.)
// B3[row][c], row in [0,1024): eo=row>>9, j=row&511. eo=0 (E): c<257 ->
//   sc*cos(2pi*2c*j/1024), c>=257 -> -2*sin(2pi*2(c-256)*j/1024). eo=1 (O):
//   c<256 -> 2*cos(2pi*(2c+1)j/1024), c>=256 -> -2*sin(2pi*(2(c-256)+1)j/1024).
// wint[j]=win[j]*CQ. frame[j]=wint[j](E[j]+O[j]), frame[j+512]=wint[j+512](E[j]-O[j]).
__global__ void prep(const float* __restrict__ x, __hip_bfloat16* __restrict__ A,
                     __hip_bfloat16* __restrict__ B3, float* __restrict__ wint) {
  int tid = threadIdx.x;
  if (blockIdx.x >= PACK_BLOCKS) {
    int idx = (blockIdx.x - PACK_BLOCKS) * 256 + tid;   // [0, 1024*512)
    int row = idx >> 9, c = idx & 511;
    int eo = row >> 9, j = row & 511;
    int f, isSin;
    if (!eo) {
      if (c < 257) { f = 2 * c; isSin = 0; } else { f = 2 * (c - 256); isSin = 1; }
    } else {
      if (c < 256) { f = 2 * c + 1; isSin = 0; } else { f = 2 * (c - 256) + 1; isSin = 1; }
    }
    const float w0 = 6.283185307179586f / 1024.f;
    int ph = (f * j) & 1023;
    float si, co;
    __sincosf((float)ph * w0, &si, &co);
    float sc = (f == 0 || f == 512) ? 1.f : 2.f;
    B3[idx] = __float2bfloat16(isSin ? -si * sc : co * sc);
    if (idx < 1024)
      wint[idx] = (0.5f - 0.5f * __cosf((float)idx * w0)) * CQ;
    return;
  }
  __shared__ float2 tile[64][65];
  int w = blockIdx.x;
  int b = w >> 7, fy = (w >> 4) & 7, tx = w & 15;
  int f0 = fy * 64, t0 = tx * 64;
  int tl = tid & 63, th = tid >> 6;
#pragma unroll
  for (int r = 0; r < 16; ++r) {
    int fl = r * 4 + th;
    tile[fl][tl] = *(const float2*)(x + (((size_t)b * 513 + f0 + fl) * 1024 + (t0 + tl)) * 2);
  }
  __syncthreads();
  int row = tid >> 2, s = tid & 3;
  float sp = 0.f;
  if (fy == 0 && s == 1)
    sp = x[(((size_t)b * 513 + 512) * 1024 + t0 + row) * 2];   // re512 -> c=256
  int cbase = (s & 1) * 256 + (s >> 1) * 512 + f0 / 2;
#pragma unroll
  for (int v = 0; v < 4; ++v) {
    bf16x8 pv;
#pragma unroll
    for (int u = 0; u < 8; ++u) {
      int e = v * 8 + u;
      float2 tv = tile[2 * e + (s >> 1)][row];
      float val = (s & 1) ? tv.y : tv.x;
      if (fy == 0 && s == 1 && e == 0) val = sp;   // replace dropped im f=0
      pv[u] = (__bf16)val;
    }
    *(bf16x8*)(A + (size_t)(b * 1024 + t0 + row) * 1024 + cbase + v * 8) = pv;
  }
}

// 256m x 256j tile, BK=64, 8 K-tiles (K=512 per E/O panel), 8 waves (2M x 4N),
// round-12-verified 4-phase counted-vmcnt schedule (T3+T4), 3-bit slot swizzle
// (rule 21), setprio (T5). Block = one (m-tile, eo, j-tile); A cols eo*512+,
// B3 rows eo*512 + j0 +. Writes raw E/O bf16 to Craw (no wint, no rank-1).
// XCD decode: 4 blocks sharing an A-panel land on one XCD (bids differ by 8).
__global__ __launch_bounds__(512, 1) void gemm8(
    const __hip_bfloat16* __restrict__ A, const __hip_bfloat16* __restrict__ B3,
    __hip_bfloat16* __restrict__ Craw) {
  __shared__ __align__(16) __hip_bfloat16 smem[65536];  // 128 KB
  int tid = threadIdx.x, lane = tid & 63, wv = tid >> 6;
  int wr = wv >> 2, wc = wv & 3;
  int xcd = blockIdx.x & 7, g = blockIdx.x >> 3;
  int m_ = xcd + 8 * (g >> 2);     // [0,64)
  int sub = g & 3;
  int eo = sub >> 1, ntile = sub & 1;
  int M0 = m_ * 256;
  int j0 = ntile * 256;
  int acol = eo * 512;             // A column base
  int brow = eo * 512 + j0;        // B3 row base

  __hip_bfloat16* sA0 = smem;
  __hip_bfloat16* sA1 = smem + 16384;
  __hip_bfloat16* sB0 = smem + 32768;
  __hip_bfloat16* sB1 = smem + 49152;

  f32x4 acc[8][4] = {};

#define SG(X, RB, RS, CB, KT, G, LB)                                           \
  {                                                                            \
    int r_ = (G) * 64 + (tid >> 3);                                            \
    int s_ = (((tid & 7) ^ (r_ & 7)) * 8);                                     \
    gload_lds16((X) + (size_t)((RB) + r_) * (RS) + (CB) + (KT) * 64 + s_,      \
                (LB) + (G) * 4096 + tid * 8);                                  \
  }
#define SGA(KT, G, LB) SG(A, M0, 1024, acol, KT, G, LB)
#define SGB(KT, G, LB) SG(B3, brow, 512, 0, KT, G, LB)
#define VMCNT(N) asm volatile("s_waitcnt vmcnt(" #N ")" ::: "memory")
#define BAR() __builtin_amdgcn_s_barrier()

#define LOADA(CA, Q)                                                           \
  _Pragma("unroll") for (int j = 0; j < 2; ++j) {                              \
    int row = wr * 128 + (2 * (Q) + j) * 16 + (lane & 15);                     \
    _Pragma("unroll") for (int ks = 0; ks < 2; ++ks)                           \
        af[j][ks] = *(const bf16x8*)&(CA)[row * 64 +                           \
            (((ks * 4 + (lane >> 4)) ^ (row & 7)) * 8)];                       \
  }
#define MFMAQ(Q)                                                               \
  __builtin_amdgcn_s_setprio(1);                                               \
  _Pragma("unroll") for (int j = 0; j < 2; ++j)                                \
  _Pragma("unroll") for (int ks = 0; ks < 2; ++ks)                             \
  _Pragma("unroll") for (int ni = 0; ni < 4; ++ni)                             \
      acc[2 * (Q) + j][ni] = __builtin_amdgcn_mfma_f32_16x16x32_bf16(          \
          af[j][ks], bfr[ks][ni], acc[2 * (Q) + j][ni], 0, 0, 0);              \
  __builtin_amdgcn_s_setprio(0);

#define TILE(CA, CB, NA, NBUF, K1, DOST)                                       \
  {                                                                            \
    bf16x8 bfr[2][4], af[2][2];                                                \
    _Pragma("unroll") for (int ni = 0; ni < 4; ++ni) {                         \
      int row = wc * 64 + ni * 16 + (lane & 15);                               \
      _Pragma("unroll") for (int ks = 0; ks < 2; ++ks)                         \
          bfr[ks][ni] = *(const bf16x8*)&(CB)[row * 64 +                       \
              (((ks * 4 + (lane >> 4)) ^ (row & 7)) * 8)];                     \
    }                                                                          \
    LOADA(CA, 0);                                                              \
    if (DOST) { SGB(K1, 0, NBUF); SGB(K1, 1, NBUF); }                          \
    BAR(); MFMAQ(0); BAR();                                                    \
    LOADA(CA, 1);                                                              \
    if (DOST) { SGB(K1, 2, NBUF); SGB(K1, 3, NBUF); }                          \
    BAR(); MFMAQ(1);                                                           \
    if (DOST) { VMCNT(4); } else { VMCNT(0); }                                 \
    BAR();                                                                     \
    LOADA(CA, 2);                                                              \
    if (DOST) { SGA(K1, 0, NA); SGA(K1, 2, NA); }                              \
    BAR(); MFMAQ(2); BAR();                                                    \
    LOADA(CA, 3);                                                              \
    if (DOST) { SGA(K1, 1, NA); SGA(K1, 3, NA); }                              \
    BAR(); MFMAQ(3);                                                           \
    if (DOST) { VMCNT(2); }                                                    \
    BAR();                                                                     \
  }

  // prologue: tile 0 -> buf0 (order: B g0..g3, A g0,g2 then g1,g3)
  SGB(0, 0, sB0); SGB(0, 1, sB0);
  SGB(0, 2, sB0); SGB(0, 3, sB0);
  SGA(0, 0, sA0); SGA(0, 2, sA0);
  SGA(0, 1, sA0); SGA(0, 3, sA0);
  VMCNT(2);   // B g0..3 + A g0,g2 landed; A g1,g3 still in flight
  BAR();

#pragma unroll
  for (int tt = 0; tt < 3; ++tt) {
    TILE(sA0, sB0, sA1, sB1, 2 * tt + 1, 1);
    TILE(sA1, sB1, sA0, sB0, 2 * tt + 2, 1);
  }
  TILE(sA0, sB0, sA1, sB1, 7, 1);    // tile 6 (stages tile 7)
  TILE(sA1, sB1, sA0, sB0, 0, 0);    // tile 7 (no stage; mid VMCNT(0))

  // epilogue: raw acc -> bf16 via LDS bounce -> coalesced stores
  __hip_bfloat16* ct = smem;
#pragma unroll
  for (int mi = 0; mi < 8; ++mi) {
    int rbase = wr * 128 + mi * 16 + (lane >> 4) * 4;
#pragma unroll
    for (int ni = 0; ni < 4; ++ni) {
      int col = wc * 64 + ni * 16 + (lane & 15);
#pragma unroll
      for (int r = 0; r < 4; ++r)
        ct[(rbase + r) * 256 + col] = __float2bfloat16(acc[mi][ni][r]);
    }
  }
  BAR();
#pragma unroll
  for (int k = 0; k < 16; ++k) {
    int row = k * 16 + (tid >> 5);
    int c0 = (tid & 31) * 8;
    *(int4*)(Craw + (size_t)(M0 + row) * 1024 + eo * 512 + j0 + c0) =
        *(const int4*)&ct[row * 256 + c0];
  }
#undef SG
#undef SGA
#undef SGB
#undef VMCNT
#undef BAR
#undef LOADA
#undef MFMAQ
#undef TILE
}

// OLA + E/O butterfly: frame[m][j] = j<512 ? wint[j]*(E[j]+O[j])
//   : wint[j]*(E[j-512]-O[j-512]); E = Craw[m][0:512], O = Craw[m][512:1024].
// out[b][256q+r] = sum_{t=q-3..q, clamped} frame[b*1024+t][(256q+r)-256t].
// Interior q: rows q,q-2 use cols {r0, 512+r0}; rows q-1,q-3 use {256+r0, 768+r0}.
__global__ void ola2(const __hip_bfloat16* __restrict__ C, const float* __restrict__ wint,
                     float* __restrict__ out) {
  int q = blockIdx.x;                        // 0..1026
  int b = blockIdx.y * 8 + (threadIdx.x >> 5);
  int r0 = (threadIdx.x & 31) * 8;
  size_t outl = (size_t)b * LOUT + q * 256 + r0;
  if (q >= 3 && q < 1024) {
    size_t m0 = ((size_t)b * 1024 + q) * 1024;
    bf16x8 e0 = *(const bf16x8*)&C[m0 + r0];                  // row q,   j=r0      (+)
    bf16x8 o0 = *(const bf16x8*)&C[m0 + 512 + r0];
    bf16x8 e1 = *(const bf16x8*)&C[m0 - 1024 + 256 + r0];     // row q-1, j=256+r0  (+)
    bf16x8 o1 = *(const bf16x8*)&C[m0 - 1024 + 768 + r0];
    bf16x8 e2 = *(const bf16x8*)&C[m0 - 2048 + r0];           // row q-2, j=512+r0  (-)
    bf16x8 o2 = *(const bf16x8*)&C[m0 - 2048 + 512 + r0];
    bf16x8 e3 = *(const bf16x8*)&C[m0 - 3072 + 256 + r0];     // row q-3, j=768+r0  (-)
    bf16x8 o3 = *(const bf16x8*)&C[m0 - 3072 + 768 + r0];
    float wv[4][8];
#pragma unroll
    for (int h = 0; h < 4; ++h) {
      *(float4*)&wv[h][0] = *(const float4*)&wint[h * 256 + r0];
      *(float4*)&wv[h][4] = *(const float4*)&wint[h * 256 + r0 + 4];
    }
    float res[8];
#pragma unroll
    for (int e = 0; e < 8; ++e)
      res[e] = wv[0][e] * ((float)e0[e] + (float)o0[e])
             + wv[1][e] * ((float)e1[e] + (float)o1[e])
             + wv[2][e] * ((float)e2[e] - (float)o2[e])
             + wv[3][e] * ((float)e3[e] - (float)o3[e]);
    *(float4*)(out + outl) = make_float4(res[0], res[1], res[2], res[3]);
    *(float4*)(out + outl + 4) = make_float4(res[4], res[5], res[6], res[7]);
    return;
  }
#pragma unroll
  for (int e = 0; e < 8; ++e) {
    int l = q * 256 + r0 + e;
    int thi = l >> 8; if (thi > 1023) thi = 1023;
    int tlo = (l - 768) >> 8; if (tlo < 0) tlo = 0;
    float s = 0.f;
    for (int t = tlo; t <= thi; ++t) {
      int j = l - (t << 8);
      size_t m = ((size_t)b * 1024 + t) * 1024;
      float fr;
      if (j < 512)
        fr = wint[j] * (__bfloat162float(C[m + j]) + __bfloat162float(C[m + 512 + j]));
      else
        fr = wint[j] * (__bfloat162float(C[m + j - 512]) - __bfloat162float(C[m + j]));
      s += fr;
    }
    out[outl + e] = s;
  }
}

extern "C" void kernel_launch(void* const* d_in, const int* in_sizes, int n_in,
                              void* d_out, int out_size, void* d_ws, size_t ws_size,
                              hipStream_t stream) {
  (void)in_sizes; (void)n_in; (void)out_size; (void)ws_size;
  const float* x = (const float*)d_in[0];
  float* out = (float*)d_out;
  char* ws = (char*)d_ws;
  size_t oA  = 0;
  size_t oB3 = oA + (size_t)MM * 1024 * 2;         // 33.55 MB
  size_t oW  = oB3 + (size_t)1024 * 512 * 2;       // +1 MB
  size_t oC  = oW + 1024 * 4;
  __hip_bfloat16* A  = (__hip_bfloat16*)(ws + oA);
  __hip_bfloat16* B3 = (__hip_bfloat16*)(ws + oB3);
  float* wint = (float*)(ws + oW);
  __hip_bfloat16* Craw = (__hip_bfloat16*)(ws + oC);

  prep<<<dim3(PACK_BLOCKS + 2048), dim3(256), 0, stream>>>(x, A, B3, wint);
  gemm8<<<dim3(256), dim3(512), 0, stream>>>(A, B3, Craw);
  ola2<<<dim3(1027, 2), dim3(256), 0, stream>>>(Craw, wint, out);
}

// Round 17
// 59.446 us; speedup vs baseline: 1.0903x; 1.0903x over previous
//
#include <hip/hip_runtime.h>
#include <hip/hip_bf16.h>

#define HOP 256
#define NB 16
#define NT 1024
#define MM (NB*NT)                 // 16384
#define LOUT ((NT-1)*HOP + 1024)   // 262912
#define CQ (2.0f/(3.0f*1024.0f))   // (HOP/sum(win^2))/NFFT
#define PACK_BLOCKS 2048           // 16 b x 8 f-tiles x 16 t-tiles

typedef __bf16 bf16x8 __attribute__((ext_vector_type(8)));
typedef float f32x4 __attribute__((ext_vector_type(4)));

__device__ __forceinline__ void gload_lds16(const void* g, void* l) {
  __builtin_amdgcn_global_load_lds(
      (const __attribute__((address_space(1))) void*)g,
      (__attribute__((address_space(3))) void*)l, 16, 0, 0);
}

// Radix-2 frequency split (verified round-14/15 prep, unchanged).
// A2[m][c]: c in [0,257): re f=2c | [257,512): im f=2(c-256) | [512,768): re f=2(c-512)+1
//   | [768,1024): im f=2(c-768)+1.  (im f=0 dropped: zero kernel; re f=512 at c=256.)
// B3[row][c], row in [0,1024): nt=row>>8, i=row&255; i<128: E-row j=nt*128+i,
//   i>=128: O-row j=nt*128+i-128. wint[j]=win[j]*CQ.
// frame[j]=wint[j]*(E+O), frame[j+512]=wint[j+512]*(E-O).
__global__ void prep(const float* __restrict__ x, __hip_bfloat16* __restrict__ A,
                     __hip_bfloat16* __restrict__ B3, float* __restrict__ wint) {
  int tid = threadIdx.x;
  if (blockIdx.x >= PACK_BLOCKS) {
    int idx = (blockIdx.x - PACK_BLOCKS) * 256 + tid;   // [0, 1024*512)
    int row = idx >> 9, c = idx & 511;
    int i = row & 255, nt = row >> 8;
    int oddh = i >> 7;
    int j = nt * 128 + (i & 127);
    int f, isSin;
    if (!oddh) {
      if (c < 257) { f = 2 * c; isSin = 0; } else { f = 2 * (c - 256); isSin = 1; }
    } else {
      if (c < 256) { f = 2 * c + 1; isSin = 0; } else { f = 2 * (c - 256) + 1; isSin = 1; }
    }
    const float w0 = 6.283185307179586f / 1024.f;
    int ph = (f * j) & 1023;
    float si, co;
    __sincosf((float)ph * w0, &si, &co);
    float sc = (f == 0 || f == 512) ? 1.f : 2.f;
    B3[idx] = __float2bfloat16(isSin ? -si * sc : co * sc);
    if (idx < 1024)
      wint[idx] = (0.5f - 0.5f * __cosf((float)idx * w0)) * CQ;
    return;
  }
  __shared__ float2 tile[64][65];
  int w = blockIdx.x;
  int b = w >> 7, fy = (w >> 4) & 7, tx = w & 15;
  int f0 = fy * 64, t0 = tx * 64;
  int tl = tid & 63, th = tid >> 6;
#pragma unroll
  for (int r = 0; r < 16; ++r) {
    int fl = r * 4 + th;
    tile[fl][tl] = *(const float2*)(x + (((size_t)b * 513 + f0 + fl) * 1024 + (t0 + tl)) * 2);
  }
  __syncthreads();
  int row = tid >> 2, s = tid & 3;
  float sp = 0.f;
  if (fy == 0 && s == 1)
    sp = x[(((size_t)b * 513 + 512) * 1024 + t0 + row) * 2];   // re512 -> c=256
  int cbase = (s & 1) * 256 + (s >> 1) * 512 + f0 / 2;
#pragma unroll
  for (int v = 0; v < 4; ++v) {
    bf16x8 pv;
#pragma unroll
    for (int u = 0; u < 8; ++u) {
      int e = v * 8 + u;
      float2 tv = tile[2 * e + (s >> 1)][row];
      float val = (s & 1) ? tv.y : tv.x;
      if (fy == 0 && s == 1 && e == 0) val = sp;   // replace dropped im f=0
      pv[u] = (__bf16)val;
    }
    *(bf16x8*)(A + (size_t)(b * 1024 + t0 + row) * 1024 + cbase + v * 8) = pv;
  }
}

// 128m x 128j tile, BK=64, 4 waves (2M x 2N, wave-tile 64x64), 64 KB LDS ->
// 2 blocks/CU (8 waves/CU, same occupancy as round 15 but 33% fewer LDS frag
// reads per CU and 4-wave barriers). Stage-next at tile START, 1 barrier/tile,
// VMCNT(0) drain; 3-bit slot swizzle (rule 21), setprio (T5), XCD co-location.
// K-tiles 0..7: E (A cols 0-511), 8..15: O (A cols 512-1023).
// Epilogue butterfly: frame[j]=wint[j](E+O), frame[j+512]=wint[j+512](E-O).
__global__ __launch_bounds__(256, 2) void gemm8(
    const __hip_bfloat16* __restrict__ A, const __hip_bfloat16* __restrict__ B3,
    const float* __restrict__ wint, __hip_bfloat16* __restrict__ C) {
  __shared__ __align__(16) __hip_bfloat16 smem[32768];  // 64 KB
  int tid = threadIdx.x, lane = tid & 63, wv = tid >> 6;  // wv 0..3
  int wr = wv >> 1, wc = wv & 1;
  int q = blockIdx.x >> 3, xcd = blockIdx.x & 7;
  int m_ = xcd + 8 * (q >> 2);     // [0,128): same m_ -> 4 consecutive bids, 1 XCD
  int nt = q & 3;
  int M0 = m_ * 128;
  int j0 = nt * 128;

  __hip_bfloat16* sA0 = smem;                // 128x64
  __hip_bfloat16* sA1 = smem + 8192;
  __hip_bfloat16* sB0 = smem + 16384;        // 128x64
  __hip_bfloat16* sB1 = smem + 24576;

  f32x4 accE[4][4] = {};
  f32x4 accO[4][4] = {};

#define SGA(KT, G, LB)                                                         \
  {                                                                            \
    int r_ = (G) * 32 + (tid >> 3);                                            \
    int s_ = (((tid & 7) ^ (r_ & 7)) * 8);                                     \
    gload_lds16(A + (size_t)(M0 + r_) * 1024 + (KT) * 64 + s_,                 \
                (LB) + (G) * 2048 + tid * 8);                                  \
  }
#define SGB(KT, G, LB)                                                         \
  {                                                                            \
    int r_ = (G) * 32 + (tid >> 3);                                            \
    int s_ = (((tid & 7) ^ (r_ & 7)) * 8);                                     \
    gload_lds16(B3 + (size_t)(nt * 256 + ((KT) >= 8 ? 128 : 0) + r_) * 512 +   \
                    ((KT) & 7) * 64 + s_,                                      \
                (LB) + (G) * 2048 + tid * 8);                                  \
  }
#define VMCNT0() asm volatile("s_waitcnt vmcnt(0)" ::: "memory")
#define BAR() __builtin_amdgcn_s_barrier()

// One K-tile: stage next tile FIRST (other buffer), 16 ds_reads, 32 MFMA,
// drain + single barrier.
#define TILE(CA, CB, NA, NBUF, K1, DOST, ACC)                                  \
  {                                                                            \
    if (DOST) { SGB(K1, 0, NBUF); SGB(K1, 1, NBUF);                            \
                SGB(K1, 2, NBUF); SGB(K1, 3, NBUF);                            \
                SGA(K1, 0, NA); SGA(K1, 1, NA);                                \
                SGA(K1, 2, NA); SGA(K1, 3, NA); }                              \
    bf16x8 bfr[2][4], af[4][2];                                                \
    _Pragma("unroll") for (int ni = 0; ni < 4; ++ni) {                         \
      int row = wc * 64 + ni * 16 + (lane & 15);                               \
      _Pragma("unroll") for (int ks = 0; ks < 2; ++ks)                         \
          bfr[ks][ni] = *(const bf16x8*)&(CB)[row * 64 +                       \
              (((ks * 4 + (lane >> 4)) ^ (row & 7)) * 8)];                     \
    }                                                                          \
    _Pragma("unroll") for (int mi = 0; mi < 4; ++mi) {                         \
      int row = wr * 64 + mi * 16 + (lane & 15);                               \
      _Pragma("unroll") for (int ks = 0; ks < 2; ++ks)                         \
          af[mi][ks] = *(const bf16x8*)&(CA)[row * 64 +                        \
              (((ks * 4 + (lane >> 4)) ^ (row & 7)) * 8)];                     \
    }                                                                          \
    __builtin_amdgcn_s_setprio(1);                                             \
    _Pragma("unroll") for (int mi = 0; mi < 4; ++mi)                           \
    _Pragma("unroll") for (int ks = 0; ks < 2; ++ks)                           \
    _Pragma("unroll") for (int ni = 0; ni < 4; ++ni)                           \
        ACC[mi][ni] = __builtin_amdgcn_mfma_f32_16x16x32_bf16(                 \
            af[mi][ks], bfr[ks][ni], ACC[mi][ni], 0, 0, 0);                    \
    __builtin_amdgcn_s_setprio(0);                                             \
    VMCNT0();                                                                  \
    BAR();                                                                     \
  }

  // prologue: tile 0 -> buf0
  SGB(0, 0, sB0); SGB(0, 1, sB0); SGB(0, 2, sB0); SGB(0, 3, sB0);
  SGA(0, 0, sA0); SGA(0, 1, sA0); SGA(0, 2, sA0); SGA(0, 3, sA0);
  VMCNT0();
  BAR();

#pragma unroll
  for (int tt = 0; tt < 4; ++tt) {                 // tiles 0..7: E
    TILE(sA0, sB0, sA1, sB1, 2 * tt + 1, 1, accE);
    TILE(sA1, sB1, sA0, sB0, 2 * tt + 2, 1, accE);
  }
#pragma unroll
  for (int tt = 0; tt < 4; ++tt) {                 // tiles 8..15: O
    TILE(sA0, sB0, sA1, sB1, 2 * tt + 9, 1, accO);
    TILE(sA1, sB1, sA0, sB0, 2 * tt + 10, (tt < 3) ? 1 : 0, accO);
  }

  // epilogue: combine E/O with window, bounce through LDS, coalesced stores
  __hip_bfloat16* ct = smem;                 // 128 x 256 bf16 (64 KB, reuse)
  float wE[4], wO[4];
#pragma unroll
  for (int ni = 0; ni < 4; ++ni) {
    int jcol = j0 + wc * 64 + ni * 16 + (lane & 15);
    wE[ni] = wint[jcol];
    wO[ni] = wint[jcol + 512];
  }
#pragma unroll
  for (int mi = 0; mi < 4; ++mi) {
    int rbase = wr * 64 + mi * 16 + (lane >> 4) * 4;
#pragma unroll
    for (int ni = 0; ni < 4; ++ni) {
      int lc = wc * 64 + ni * 16 + (lane & 15);
#pragma unroll
      for (int r = 0; r < 4; ++r) {
        float E = accE[mi][ni][r], O = accO[mi][ni][r];
        ct[(rbase + r) * 256 + lc] = __float2bfloat16(wE[ni] * (E + O));
        ct[(rbase + r) * 256 + 128 + lc] = __float2bfloat16(wO[ni] * (E - O));
      }
    }
  }
  BAR();
#pragma unroll
  for (int k = 0; k < 16; ++k) {
    int row = k * 8 + (tid >> 5);
    int c0 = (tid & 31) * 8;
    int gcol = (c0 < 128) ? (j0 + c0) : (512 + j0 + c0 - 128);
    *(int4*)(C + (size_t)(M0 + row) * 1024 + gcol) = *(const int4*)&ct[row * 256 + c0];
  }
#undef SGA
#undef SGB
#undef VMCNT0
#undef BAR
#undef TILE
}

// OLA: out[b][256q+r] = sum_{t=q-3..q, clamped} C[b*1024+t][(256q+r)-256t].
// Interior q: 4 contiguous aligned bf16x8 spans. Edge q: clamped scalar path.
__global__ void ola2(const __hip_bfloat16* __restrict__ C, float* __restrict__ out) {
  int q = blockIdx.x;                        // 0..1026
  int b = blockIdx.y * 8 + (threadIdx.x >> 5);
  int r0 = (threadIdx.x & 31) * 8;
  size_t outl = (size_t)b * LOUT + q * 256 + r0;
  if (q >= 3 && q < 1024) {
    size_t mrow = ((size_t)b * 1024 + q) * 1024;
    bf16x8 v0 = *(const bf16x8*)&C[mrow + r0];
    bf16x8 v1 = *(const bf16x8*)&C[mrow - 1024 + 256 + r0];
    bf16x8 v2 = *(const bf16x8*)&C[mrow - 2048 + 512 + r0];
    bf16x8 v3 = *(const bf16x8*)&C[mrow - 3072 + 768 + r0];
    float res[8];
#pragma unroll
    for (int e = 0; e < 8; ++e)
      res[e] = (float)v0[e] + (float)v1[e] + (float)v2[e] + (float)v3[e];
    *(float4*)(out + outl) = make_float4(res[0], res[1], res[2], res[3]);
    *(float4*)(out + outl + 4) = make_float4(res[4], res[5], res[6], res[7]);
    return;
  }
#pragma unroll
  for (int e = 0; e < 8; ++e) {
    int l = q * 256 + r0 + e;
    int thi = l >> 8; if (thi > 1023) thi = 1023;
    int tlo = (l - 768) >> 8; if (tlo < 0) tlo = 0;
    float s = 0.f;
    for (int t = tlo; t <= thi; ++t)
      s += __bfloat162float(C[((size_t)b * 1024 + t) * 1024 + (l - (t << 8))]);
    out[outl + e] = s;
  }
}

extern "C" void kernel_launch(void* const* d_in, const int* in_sizes, int n_in,
                              void* d_out, int out_size, void* d_ws, size_t ws_size,
                              hipStream_t stream) {
  (void)in_sizes; (void)n_in; (void)out_size; (void)ws_size;
  const float* x = (const float*)d_in[0];
  float* out = (float*)d_out;
  char* ws = (char*)d_ws;
  size_t oA  = 0;
  size_t oB3 = oA + (size_t)MM * 1024 * 2;         // 33.55 MB
  size_t oW  = oB3 + (size_t)1024 * 512 * 2;       // +1 MB
  size_t oC  = oW + 1024 * 4;
  __hip_bfloat16* A  = (__hip_bfloat16*)(ws + oA);
  __hip_bfloat16* B3 = (__hip_bfloat16*)(ws + oB3);
  float* wint = (float*)(ws + oW);
  __hip_bfloat16* C  = (__hip_bfloat16*)(ws + oC);

  prep<<<dim3(PACK_BLOCKS + 2048), dim3(256), 0, stream>>>(x, A, B3, wint);
  gemm8<<<dim3(512), dim3(256), 0, stream>>>(A, B3, wint, C);
  ola2<<<dim3(1027, 2), dim3(256), 0, stream>>>(C, out);
}